// Round 11
// baseline (32.258 us; speedup 1.0000x reference)
//
#include <hip/hip_runtime.h>
#include <hip/hip_fp16.h>

#define IN_F   4096
#define OUT_F  4096
#define BATCH  32
#define NGPR   512          // groups per output row
#define BN     16           // output rows per block
#define NW     8            // waves per block
#define QPITCH 1540         // dwords per q-row in LDS (1536 + 4; 1540%32==4 -> 2-way banks)
#define NPITCH 516          // floats per norm-row in LDS (512 + 4)
#define MAGIC  0x5A5A17C3u

typedef float f32x4  __attribute__((ext_vector_type(4)));
typedef short short8 __attribute__((ext_vector_type(8)));

__device__ __forceinline__ unsigned short f2bf_u(float f) {
    return __builtin_bit_cast(unsigned short, (__bf16)f);   // RNE via v_cvt
}

__device__ __forceinline__ void gload16(const void* gsrc, void* lds) {
    __builtin_amdgcn_global_load_lds(
        (const __attribute__((address_space(1))) void*)gsrc,
        (__attribute__((address_space(3))) void*)lds, 16, 0, 0);
}

// Single dispatch. Blocks 0..31: pack x row b into apk (A-fragment layout),
// then signal F[b]=MAGIC. All blocks: r7 body; spin on F[0..31] just before
// the MFMA loop (overlapped with own staging flight).
// apk unit u = (a*128 + s)*64 + q*16 + cl  holds bf16 x[a*16+cl][s*32+q*8 .. +8]
__global__ __launch_bounds__(512, 2)
void l3b_one(const float* __restrict__ x,
             const int* __restrict__ wq3,
             const void* __restrict__ wnorm_raw,
             const float* __restrict__ bias,
             float* __restrict__ out,
             unsigned short* __restrict__ apk,
             unsigned int* __restrict__ F)
{
    __shared__ unsigned int qls[BN * QPITCH];   // raw q dwords, ~96 KB
    __shared__ float        nrm[BN][NPITCH];    // fp32 scales, 33 KB
    __shared__ float        red[NW][BATCH][17]; // 17.4 KB

    const int tid   = threadIdx.x;
    const int w     = tid >> 6;
    const int lane  = tid & 63;
    const int nbase = blockIdx.x * BN;

    const int q  = lane >> 4;   // 0..3
    const int cl = lane & 15;   // 0..15

    // ---- packer prelude: block b<32 packs x row b (512 units, 1/thread) ----
    if (blockIdx.x < 32) {
        const int rowb = blockIdx.x;
        const float4 lo = *reinterpret_cast<const float4*>(&x[rowb * IN_F + tid * 8]);
        const float4 hi = *reinterpret_cast<const float4*>(&x[rowb * IN_F + tid * 8 + 4]);
        union { unsigned short us[8]; uint4 v; } pk;
        pk.us[0] = f2bf_u(lo.x); pk.us[1] = f2bf_u(lo.y);
        pk.us[2] = f2bf_u(lo.z); pk.us[3] = f2bf_u(lo.w);
        pk.us[4] = f2bf_u(hi.x); pk.us[5] = f2bf_u(hi.y);
        pk.us[6] = f2bf_u(hi.z); pk.us[7] = f2bf_u(hi.w);
        const int c = tid, s = c >> 2, q2 = c & 3;
        const int a = rowb >> 4, cl2 = rowb & 15;
        const int unit = (a * 128 + s) * 64 + q2 * 16 + cl2;
        *reinterpret_cast<uint4*>(&apk[unit * 8]) = pk.v;
        __threadfence();
        __syncthreads();
        if (tid == 0) atomicExch(&F[rowb], MAGIC);
    }

    // ---- weight_norm dtype probe (deterministic, wave-uniform) ----
    // 0 = float32, 1 = float16 (raw), 2 = bfloat16
    const unsigned short* wn16  = (const unsigned short*)wnorm_raw;
    const float*          wn32  = (const float*)wnorm_raw;
    const unsigned int*   wnu32 = (const unsigned int*)wnorm_raw;
    int mode;
    {
        const unsigned short h = wn16[lane];
        const float v16 = __half2float(__builtin_bit_cast(__half, h));
        const float vbf = __builtin_bit_cast(float, (unsigned int)h << 16);
        const float v32 = wn32[lane];
        const int c16 = __popcll(__ballot(v16 > 0.0095f && v16 < 1.0005f));
        const int cbf = __popcll(__ballot(vbf > 0.0095f && vbf < 1.0005f));
        const int c32 = __popcll(__ballot(v32 > 0.0095f && v32 < 1.0005f));
        if (c16 >= c32 && c16 >= cbf) {
            mode = 1;
        } else if (c32 > cbf + 8) {
            mode = 0;
        } else if (cbf > c32 + 8) {
            mode = 2;
        } else {
            const int z = __popcll(__ballot((wnu32[lane] & 0x1FFFu) == 0u));
            mode = (z >= 48) ? 0 : 2;
        }
    }

    // ---- stage raw q panel (16 rows x 1536 dwords, contiguous in global) ----
    {
        const int* qg = wq3 + (long)nbase * 1536;
        #pragma unroll
        for (int rr = 0; rr < 2; ++rr) {
            const int row = w * 2 + rr;
            #pragma unroll
            for (int i = 0; i < 6; ++i) {
                const int off = i * 256 + lane * 4;
                gload16(qg + (long)row * 1536 + off, &qls[row * QPITCH + off]);
            }
        }
    }

    // ---- stage norms -> fp32 LDS (rows contiguous in global, dense) ----
    if (mode == 0) {
        const float* nb = wn32 + (long)nbase * NGPR;
        #pragma unroll
        for (int j = 0; j < 4; ++j) {
            const int f = j * 2048 + tid * 4;
            const float4 v = *reinterpret_cast<const float4*>(nb + f);
            *reinterpret_cast<float4*>(&nrm[f >> 9][f & 511]) = v;
        }
    } else {
        const unsigned short* nb = wn16 + (long)nbase * NGPR;
        #pragma unroll
        for (int j = 0; j < 2; ++j) {
            const int f = j * 4096 + tid * 8;
            union { unsigned short us[8]; uint4 v; } u;
            u.v = *reinterpret_cast<const uint4*>(nb + f);
            float4 f0, f1;
            if (mode == 1) {
                f0.x = __half2float(__builtin_bit_cast(__half, u.us[0]));
                f0.y = __half2float(__builtin_bit_cast(__half, u.us[1]));
                f0.z = __half2float(__builtin_bit_cast(__half, u.us[2]));
                f0.w = __half2float(__builtin_bit_cast(__half, u.us[3]));
                f1.x = __half2float(__builtin_bit_cast(__half, u.us[4]));
                f1.y = __half2float(__builtin_bit_cast(__half, u.us[5]));
                f1.z = __half2float(__builtin_bit_cast(__half, u.us[6]));
                f1.w = __half2float(__builtin_bit_cast(__half, u.us[7]));
            } else {
                f0.x = __builtin_bit_cast(float, (unsigned)u.us[0] << 16);
                f0.y = __builtin_bit_cast(float, (unsigned)u.us[1] << 16);
                f0.z = __builtin_bit_cast(float, (unsigned)u.us[2] << 16);
                f0.w = __builtin_bit_cast(float, (unsigned)u.us[3] << 16);
                f1.x = __builtin_bit_cast(float, (unsigned)u.us[4] << 16);
                f1.y = __builtin_bit_cast(float, (unsigned)u.us[5] << 16);
                f1.z = __builtin_bit_cast(float, (unsigned)u.us[6] << 16);
                f1.w = __builtin_bit_cast(float, (unsigned)u.us[7] << 16);
            }
            const int row = f >> 9, col = f & 511;
            *reinterpret_cast<float4*>(&nrm[row][col])     = f0;
            *reinterpret_cast<float4*>(&nrm[row][col + 4]) = f1;
        }
    }

    // ---- wait for all 32 packer blocks (overlaps own staging flight) ----
    if (tid < 32) {
        while (atomicAdd(&F[tid], 0u) != MAGIC) __builtin_amdgcn_s_sleep(16);
        __threadfence();
    }

    __syncthreads();   // drains vmcnt (global_load_lds) + lgkm; joins spin

    // ---- compute: wave w owns ksteps s = w*16 .. w*16+15 ----
    f32x4 acc0 = {0.f, 0.f, 0.f, 0.f};
    f32x4 acc1 = {0.f, 0.f, 0.f, 0.f};

    #pragma unroll 4
    for (int i = 0; i < 16; ++i) {
        const int s = w * 16 + i;
        const int g = s * 4 + q;

        const int qb = cl * QPITCH + g * 3;
        const unsigned d0 = qls[qb];
        const unsigned d1 = qls[qb + 1];
        const unsigned d2 = qls[qb + 2];
        const unsigned val = (d0 & 0xFFu) | ((d1 & 0xFFu) << 8) | ((d2 & 0xFFu) << 16);

        const float n  = nrm[cl][g];
        const float av = n * 0.285714285714285714f;   // 2n/7
        union { unsigned short us[8]; short8 v; } B;
        #pragma unroll
        for (int e = 0; e < 8; ++e) {
            const float qf = (float)((val >> (3 * e)) & 7u);
            B.us[e] = f2bf_u(fmaf(qf, av, -n));
        }

        const short8 A0 = *reinterpret_cast<const short8*>(&apk[(s * 64 + lane) * 8]);
        const short8 A1 = *reinterpret_cast<const short8*>(&apk[((128 + s) * 64 + lane) * 8]);

        acc0 = __builtin_amdgcn_mfma_f32_16x16x32_bf16(A0, B.v, acc0, 0, 0, 0);
        acc1 = __builtin_amdgcn_mfma_f32_16x16x32_bf16(A1, B.v, acc1, 0, 0, 0);
    }

    // ---- cross-wave K-reduction + bias + store ----
    #pragma unroll
    for (int i = 0; i < 4; ++i) {
        red[w][q * 4 + i][cl]      = acc0[i];
        red[w][16 + q * 4 + i][cl] = acc1[i];
    }
    __syncthreads();
    {
        const int m  = tid >> 4;   // 0..31
        const int nl = tid & 15;
        float ssum = 0.f;
        #pragma unroll
        for (int wv = 0; wv < NW; ++wv) ssum += red[wv][m][nl];
        out[m * OUT_F + nbase + nl] = ssum + bias[nbase + nl];
    }
}

extern "C" void kernel_launch(void* const* d_in, const int* in_sizes, int n_in,
                              void* d_out, int out_size, void* d_ws, size_t ws_size,
                              hipStream_t stream) {
    const float* x    = (const float*)d_in[0];
    const int*   wq3  = (const int*)d_in[1];
    const void*  wn   = (const void*)d_in[2];
    const float* bias = (const float*)d_in[3];
    float*       out  = (float*)d_out;

    unsigned short* apk = (unsigned short*)d_ws;                       // 256 KB
    unsigned int*   F   = (unsigned int*)((char*)d_ws + 262144);       // 32 flags

    l3b_one<<<dim3(OUT_F / BN), dim3(512), 0, stream>>>(x, wq3, wn, bias, out, apk, F);
}

// Round 12
// 24.987 us; speedup vs baseline: 1.2910x; 1.2910x over previous
//
#include <hip/hip_runtime.h>
#include <hip/hip_fp16.h>

#define IN_F   4096
#define OUT_F  4096
#define BATCH  32
#define NGPR   512          // groups per output row
#define BN     16           // output rows per block
#define NW     8            // waves per block
#define QPITCH 1540         // dwords per q-row in LDS (1536 + 4; 1540%32==4 -> 2-way banks)
#define NPITCH 516          // floats per norm-row in LDS (512 + 4)

typedef float f32x4  __attribute__((ext_vector_type(4)));
typedef short short8 __attribute__((ext_vector_type(8)));

__device__ __forceinline__ unsigned short f2bf_u(float f) {
    return __builtin_bit_cast(unsigned short, (__bf16)f);   // RNE via v_cvt
}

__device__ __forceinline__ void gload16(const void* gsrc, void* lds) {
    __builtin_amdgcn_global_load_lds(
        (const __attribute__((address_space(1))) void*)gsrc,
        (__attribute__((address_space(3))) void*)lds, 16, 0, 0);
}

// Single dispatch, no workspace, no inter-block dependencies.
// A-fragments are read directly from fp32 x (L2-resident) inside the MFMA
// loop and converted to bf16 in-register (formula verified in r8).
__global__ __launch_bounds__(512, 2)
void l3b_fused(const float* __restrict__ x,
               const int* __restrict__ wq3,
               const void* __restrict__ wnorm_raw,
               const float* __restrict__ bias,
               float* __restrict__ out)
{
    __shared__ unsigned int qls[BN * QPITCH];   // raw q dwords, ~96 KB
    __shared__ float        nrm[BN][NPITCH];    // fp32 scales, 33 KB
    __shared__ float        red[NW][BATCH][17]; // 17.4 KB

    const int tid   = threadIdx.x;
    const int w     = tid >> 6;
    const int lane  = tid & 63;
    const int nbase = blockIdx.x * BN;

    const int q  = lane >> 4;   // 0..3
    const int cl = lane & 15;   // 0..15

    // ---- weight_norm dtype probe (deterministic, wave-uniform) ----
    // 0 = float32, 1 = float16 (raw), 2 = bfloat16
    const unsigned short* wn16  = (const unsigned short*)wnorm_raw;
    const float*          wn32  = (const float*)wnorm_raw;
    const unsigned int*   wnu32 = (const unsigned int*)wnorm_raw;
    int mode;
    {
        const unsigned short h = wn16[lane];
        const float v16 = __half2float(__builtin_bit_cast(__half, h));
        const float vbf = __builtin_bit_cast(float, (unsigned int)h << 16);
        const float v32 = wn32[lane];
        const int c16 = __popcll(__ballot(v16 > 0.0095f && v16 < 1.0005f));
        const int cbf = __popcll(__ballot(vbf > 0.0095f && vbf < 1.0005f));
        const int c32 = __popcll(__ballot(v32 > 0.0095f && v32 < 1.0005f));
        if (c16 >= c32 && c16 >= cbf) {
            mode = 1;
        } else if (c32 > cbf + 8) {
            mode = 0;
        } else if (cbf > c32 + 8) {
            mode = 2;
        } else {
            const int z = __popcll(__ballot((wnu32[lane] & 0x1FFFu) == 0u));
            mode = (z >= 48) ? 0 : 2;
        }
    }

    // ---- stage raw q panel (16 rows x 1536 dwords, contiguous in global) ----
    // wave w stages rows 2w,2w+1; 1 KB contiguous in global AND LDS per inst.
    {
        const int* qg = wq3 + (long)nbase * 1536;
        #pragma unroll
        for (int rr = 0; rr < 2; ++rr) {
            const int row = w * 2 + rr;
            #pragma unroll
            for (int i = 0; i < 6; ++i) {
                const int off = i * 256 + lane * 4;
                gload16(qg + (long)row * 1536 + off, &qls[row * QPITCH + off]);
            }
        }
    }

    // ---- stage norms -> fp32 LDS (rows contiguous in global, dense) ----
    if (mode == 0) {
        const float* nb = wn32 + (long)nbase * NGPR;
        #pragma unroll
        for (int j = 0; j < 4; ++j) {
            const int f = j * 2048 + tid * 4;
            const float4 v = *reinterpret_cast<const float4*>(nb + f);
            *reinterpret_cast<float4*>(&nrm[f >> 9][f & 511]) = v;
        }
    } else {
        const unsigned short* nb = wn16 + (long)nbase * NGPR;
        #pragma unroll
        for (int j = 0; j < 2; ++j) {
            const int f = j * 4096 + tid * 8;
            union { unsigned short us[8]; uint4 v; } u;
            u.v = *reinterpret_cast<const uint4*>(nb + f);
            float4 f0, f1;
            if (mode == 1) {
                f0.x = __half2float(__builtin_bit_cast(__half, u.us[0]));
                f0.y = __half2float(__builtin_bit_cast(__half, u.us[1]));
                f0.z = __half2float(__builtin_bit_cast(__half, u.us[2]));
                f0.w = __half2float(__builtin_bit_cast(__half, u.us[3]));
                f1.x = __half2float(__builtin_bit_cast(__half, u.us[4]));
                f1.y = __half2float(__builtin_bit_cast(__half, u.us[5]));
                f1.z = __half2float(__builtin_bit_cast(__half, u.us[6]));
                f1.w = __half2float(__builtin_bit_cast(__half, u.us[7]));
            } else {
                f0.x = __builtin_bit_cast(float, (unsigned)u.us[0] << 16);
                f0.y = __builtin_bit_cast(float, (unsigned)u.us[1] << 16);
                f0.z = __builtin_bit_cast(float, (unsigned)u.us[2] << 16);
                f0.w = __builtin_bit_cast(float, (unsigned)u.us[3] << 16);
                f1.x = __builtin_bit_cast(float, (unsigned)u.us[4] << 16);
                f1.y = __builtin_bit_cast(float, (unsigned)u.us[5] << 16);
                f1.z = __builtin_bit_cast(float, (unsigned)u.us[6] << 16);
                f1.w = __builtin_bit_cast(float, (unsigned)u.us[7] << 16);
            }
            const int row = f >> 9, col = f & 511;
            *reinterpret_cast<float4*>(&nrm[row][col])     = f0;
            *reinterpret_cast<float4*>(&nrm[row][col + 4]) = f1;
        }
    }

    __syncthreads();   // drains vmcnt (global_load_lds) + lgkm

    // ---- compute: wave w owns ksteps s = w*16 .. w*16+15 ----
    f32x4 acc0 = {0.f, 0.f, 0.f, 0.f};
    f32x4 acc1 = {0.f, 0.f, 0.f, 0.f};

    const float* xr0 = x + cl        * IN_F;   // batch row cl
    const float* xr1 = x + (cl + 16) * IN_F;   // batch row cl+16

    #pragma unroll 4
    for (int i = 0; i < 16; ++i) {
        const int s = w * 16 + i;
        const int g = s * 4 + q;

        // re-assemble 24-bit group word from 3 raw dwords (one byte each)
        const int qb = cl * QPITCH + g * 3;
        const unsigned d0 = qls[qb];
        const unsigned d1 = qls[qb + 1];
        const unsigned d2 = qls[qb + 2];
        const unsigned val = (d0 & 0xFFu) | ((d1 & 0xFFu) << 8) | ((d2 & 0xFFu) << 16);

        const float n  = nrm[cl][g];
        const float av = n * 0.285714285714285714f;   // 2n/7
        union { unsigned short us[8]; short8 v; } B;
        #pragma unroll
        for (int e = 0; e < 8; ++e) {
            const float qf = (float)((val >> (3 * e)) & 7u);
            B.us[e] = f2bf_u(fmaf(qf, av, -n));
        }

        // A fragments straight from fp32 x (L2-warm), convert in-register
        const int kg = s * 32 + q * 8;
        const float4 a0lo = *reinterpret_cast<const float4*>(xr0 + kg);
        const float4 a0hi = *reinterpret_cast<const float4*>(xr0 + kg + 4);
        const float4 a1lo = *reinterpret_cast<const float4*>(xr1 + kg);
        const float4 a1hi = *reinterpret_cast<const float4*>(xr1 + kg + 4);
        union { unsigned short us[8]; short8 v; } A0, A1;
        A0.us[0] = f2bf_u(a0lo.x); A0.us[1] = f2bf_u(a0lo.y);
        A0.us[2] = f2bf_u(a0lo.z); A0.us[3] = f2bf_u(a0lo.w);
        A0.us[4] = f2bf_u(a0hi.x); A0.us[5] = f2bf_u(a0hi.y);
        A0.us[6] = f2bf_u(a0hi.z); A0.us[7] = f2bf_u(a0hi.w);
        A1.us[0] = f2bf_u(a1lo.x); A1.us[1] = f2bf_u(a1lo.y);
        A1.us[2] = f2bf_u(a1lo.z); A1.us[3] = f2bf_u(a1lo.w);
        A1.us[4] = f2bf_u(a1hi.x); A1.us[5] = f2bf_u(a1hi.y);
        A1.us[6] = f2bf_u(a1hi.z); A1.us[7] = f2bf_u(a1hi.w);

        acc0 = __builtin_amdgcn_mfma_f32_16x16x32_bf16(A0.v, B.v, acc0, 0, 0, 0);
        acc1 = __builtin_amdgcn_mfma_f32_16x16x32_bf16(A1.v, B.v, acc1, 0, 0, 0);
    }

    // ---- cross-wave K-reduction + bias + store ----
    #pragma unroll
    for (int i = 0; i < 4; ++i) {
        red[w][q * 4 + i][cl]      = acc0[i];
        red[w][16 + q * 4 + i][cl] = acc1[i];
    }
    __syncthreads();
    {
        const int m  = tid >> 4;   // 0..31
        const int nl = tid & 15;
        float ssum = 0.f;
        #pragma unroll
        for (int wv = 0; wv < NW; ++wv) ssum += red[wv][m][nl];
        out[m * OUT_F + nbase + nl] = ssum + bias[nbase + nl];
    }
}

extern "C" void kernel_launch(void* const* d_in, const int* in_sizes, int n_in,
                              void* d_out, int out_size, void* d_ws, size_t ws_size,
                              hipStream_t stream) {
    const float* x    = (const float*)d_in[0];
    const int*   wq3  = (const int*)d_in[1];
    const void*  wn   = (const void*)d_in[2];
    const float* bias = (const float*)d_in[3];
    float*       out  = (float*)d_out;

    l3b_fused<<<dim3(OUT_F / BN), dim3(512), 0, stream>>>(x, wq3, wn, bias, out);
}